// Round 3
// baseline (7078.424 us; speedup 1.0000x reference)
//
#include <hip/hip_runtime.h>
#include <math.h>

#define BB 8
#define TT 1024
#define DD 512
#define NT 64       // tape rows
#define NSL 8       // slices (blocks per batch)
#define DSL 64      // slice width in d
#define PITCH 68    // LDS pitch for tape rows

typedef unsigned int u32;

// ---------------- atomic tag ops (agent scope, relaxed) ----------------
static __device__ __forceinline__ u32 aload32(const u32* p) {
    return __hip_atomic_load(p, __ATOMIC_RELAXED, __HIP_MEMORY_SCOPE_AGENT);
}
static __device__ __forceinline__ void astore32(u32* p, u32 v) {
    __hip_atomic_store(p, v, __ATOMIC_RELAXED, __HIP_MEMORY_SCOPE_AGENT);
}

static __device__ __forceinline__ float redux8(float v) {
    v += __shfl_xor(v, 1);
    v += __shfl_xor(v, 2);
    v += __shfl_xor(v, 4);
    return v;
}
static __device__ __forceinline__ float sum64(float v) {
    #pragma unroll
    for (int off = 32; off > 0; off >>= 1) v += __shfl_xor(v, off);
    return v;
}
// branch-free tanh: (e^{2x}-1)/(e^{2x}+1), clamped so e never overflows
static __device__ __forceinline__ float fast_tanh(float x) {
    float xc = fminf(fmaxf(x, -15.f), 15.f);
    float e = __expf(2.f * xc);
    return (e - 1.f) / (e + 1.f);
}

// dot of 64 resident weights with 64 LDS floats
static __device__ __forceinline__ float dot64(const float4 (&w)[16], const float* hr) {
    float a0 = 0.f, a1 = 0.f, a2 = 0.f, a3 = 0.f;
    #pragma unroll
    for (int j = 0; j < 16; j += 4) {
        float4 h0 = *(const float4*)(hr + 4 * (j + 0));
        float4 h1 = *(const float4*)(hr + 4 * (j + 1));
        float4 h2 = *(const float4*)(hr + 4 * (j + 2));
        float4 h3 = *(const float4*)(hr + 4 * (j + 3));
        a0 += w[j + 0].x * h0.x + w[j + 0].y * h0.y + w[j + 0].z * h0.z + w[j + 0].w * h0.w;
        a1 += w[j + 1].x * h1.x + w[j + 1].y * h1.y + w[j + 1].z * h1.z + w[j + 1].w * h1.w;
        a2 += w[j + 2].x * h2.x + w[j + 2].y * h2.y + w[j + 2].z * h2.z + w[j + 2].w * h2.w;
        a3 += w[j + 3].x * h3.x + w[j + 3].y * h3.y + w[j + 3].z * h3.z + w[j + 3].w * h3.w;
    }
    return (a0 + a1) + (a2 + a3);
}

// ---------------- projection GEMM (unchanged) ----------------
__global__ __launch_bounds__(256) void proj_kernel(const float* __restrict__ x,
                                                   const float* __restrict__ Wxz,
                                                   float* __restrict__ xp,
                                                   float* __restrict__ z) {
    __shared__ float As[16][66];
    __shared__ float Bs[16][66];
    const int m0 = blockIdx.x * 64;
    const int n0 = blockIdx.y * 64;
    const int tid = threadIdx.x;
    const int tm = tid / 16, tn = tid % 16;
    float c[4][4] = {};
    for (int k0 = 0; k0 < 512; k0 += 16) {
        const int r = tid >> 2, c4 = (tid & 3) * 4;
        float4 a4 = *(const float4*)(x + (size_t)(m0 + r) * 512 + k0 + c4);
        float4 b4 = *(const float4*)(Wxz + (size_t)(n0 + r) * 512 + k0 + c4);
        As[c4 + 0][r] = a4.x; As[c4 + 1][r] = a4.y; As[c4 + 2][r] = a4.z; As[c4 + 3][r] = a4.w;
        Bs[c4 + 0][r] = b4.x; Bs[c4 + 1][r] = b4.y; Bs[c4 + 2][r] = b4.z; Bs[c4 + 3][r] = b4.w;
        __syncthreads();
        #pragma unroll
        for (int k = 0; k < 16; ++k) {
            float a0 = As[k][tm * 4 + 0], a1 = As[k][tm * 4 + 1];
            float a2 = As[k][tm * 4 + 2], a3 = As[k][tm * 4 + 3];
            float b0 = Bs[k][tn * 4 + 0], b1 = Bs[k][tn * 4 + 1];
            float b2 = Bs[k][tn * 4 + 2], b3 = Bs[k][tn * 4 + 3];
            c[0][0] += a0 * b0; c[0][1] += a0 * b1; c[0][2] += a0 * b2; c[0][3] += a0 * b3;
            c[1][0] += a1 * b0; c[1][1] += a1 * b1; c[1][2] += a1 * b2; c[1][3] += a1 * b3;
            c[2][0] += a2 * b0; c[2][1] += a2 * b1; c[2][2] += a2 * b2; c[2][3] += a2 * b3;
            c[3][0] += a3 * b0; c[3][1] += a3 * b1; c[3][2] += a3 * b2; c[3][3] += a3 * b3;
        }
        __syncthreads();
    }
    #pragma unroll
    for (int i = 0; i < 4; ++i) {
        const int m = m0 + tm * 4 + i;
        #pragma unroll
        for (int j = 0; j < 4; ++j) {
            const int e = n0 + tn * 4 + j;
            if (e < 512) xp[(size_t)m * 512 + e] = c[i][j];
            else         z[(size_t)m * 512 + (e - 512)] = c[i][j];
        }
    }
}

// ---------------- recurrence: 64 blocks = 8 batches x 8 d-slices ----------------
// Sync: plain coalesced payload stores + release fence + ONE atomic tag/slice;
// consumers poll 8 tags (8 lane-ops), acquire fence (L2 inv), plain line loads.
__global__ __launch_bounds__(512, 2) void rec_kernel(
    const float* __restrict__ tape0, const float* __restrict__ hwork0,
    const float* __restrict__ W_h, const float* __restrict__ b_h,
    const float* __restrict__ W_write,
    const float* __restrict__ g_z, const float* __restrict__ g_r,
    const float* __restrict__ g_h, const float* __restrict__ b_gate,
    const float* __restrict__ Zbuf,
    float* __restrict__ out, float* __restrict__ tape_out,
    u32* tag1, u32* tag2, float* hbuf, float* pbuf) {
    const int b = blockIdx.x & 7;
    const int s = blockIdx.x >> 3;
    const int tid = threadIdx.x;
    const int row = tid >> 3;       // 0..63
    const int l = tid & 7;          // 0..7
    const int lane = tid & 63;
    const int wv_id = tid >> 6;     // wave index 0..7
    const int d0 = s * DSL;
    const int drow = d0 + row;
    const float scale = 0.044194173824159216f;  // 1/sqrt(512)

    __shared__ __attribute__((aligned(16))) float tape[NT][PITCH];
    __shared__ __attribute__((aligned(16))) float hw2[8][PITCH];
    __shared__ __attribute__((aligned(16))) float red[8][PITCH];
    __shared__ __attribute__((aligned(16))) float hn_s[DSL];
    __shared__ __attribute__((aligned(16))) float wv_s[DSL];
    __shared__ __attribute__((aligned(16))) float hh_s[DSL];
    __shared__ __attribute__((aligned(16))) float pws_s[DSL];
    __shared__ __attribute__((aligned(16))) float ps0_s[DSL];
    __shared__ __attribute__((aligned(16))) float a_l[NT];
    __shared__ __attribute__((aligned(16))) float r_l[NT];   // c1 = r*(1-a)
    __shared__ __attribute__((aligned(16))) float rv[DSL];
    __shared__ __attribute__((aligned(16))) float xp_s[DSL];
    __shared__ __attribute__((aligned(16))) float z_s[DSL];
    __shared__ __attribute__((aligned(16))) float bh_s[DSL];
    __shared__ float c2_s;

    // tag addressing: [buf][batch][slice], 64B apart (own cache line each)
    #define TAG(base, buf, bb, ss) ((base) + (((buf) * 8 + (bb)) * 8 + (ss)) * 16)
    // pbuf slot: [buf][batch][slice] * 256 floats (64 float2 pairs + hwv@128)
    #define PSLOT(buf, ss) (pbuf + (((buf) * 8 + b) * 8 + (ss)) * 256)

    // --- resident weights ---
    float4 wh[16], ww[16];
    {
        const float4* w1 = (const float4*)(W_h + (size_t)drow * DD + l * 64);
        const float4* w2 = (const float4*)(W_write + (size_t)drow * DD + l * 64);
        #pragma unroll
        for (int j = 0; j < 16; ++j) wh[j] = w1[j];
        #pragma unroll
        for (int j = 0; j < 16; ++j) ww[j] = w2[j];
    }
    const int de = (tid >= 64 && tid < 128) ? (tid - 64) : 0;
    const float gzr = g_z[d0 + de], grr = g_r[d0 + de], ghr = g_h[d0 + de], bgr = b_gate[d0 + de];

    // --- init LDS ---
    {
        const float4* tsrc = (const float4*)(tape0 + ((size_t)(b * NT + row)) * DD + d0 + l * 8);
        float4 t0 = tsrc[0], t1 = tsrc[1];
        *(float4*)&tape[row][l * 8] = t0;
        *(float4*)&tape[row][l * 8 + 4] = t1;
    }
    if (tid < 128) {
        float4 h4 = *(const float4*)(hwork0 + (size_t)b * DD + tid * 4);
        const int e = tid * 4;
        *(float4*)&hw2[e >> 6][e & 63] = h4;
    } else if (tid < 192) {
        bh_s[tid - 128] = b_h[d0 + (tid - 128)];
    } else if (tid < 256) {
        wv_s[tid - 192] = 0.f;
    }
    if (tid == 0) c2_s = 0.f;
    __syncthreads();

    // --- init: s0 partials (h_work . tape rows) + hh = W_h . h_work ---
    {
        float acc0 = 0.f;
        #pragma unroll
        for (int i = 0; i < 8; ++i) {
            const int dl = l * 8 + i;
            const int e = d0 + dl;
            acc0 += hw2[e >> 6][e & 63] * tape[row][dl];
        }
        acc0 = redux8(acc0);
        float hh = dot64(wh, &hw2[l][0]);
        hh = redux8(hh);
        if (l == 0) { ps0_s[row] = acc0; hh_s[row] = hh; }
    }
    __syncthreads();
    // --- init publish (buf 0, tag 1) + poll ---
    if (tid < 64) {
        float* ps = PSLOT(0, s);
        float2 pp; pp.x = 0.f; pp.y = ps0_s[lane];
        ((float2*)ps)[lane] = pp;
        if (lane == 0) ps[128] = 0.f;
        __builtin_amdgcn_fence(__ATOMIC_RELEASE, "agent");
        if (lane == 0) astore32(TAG(tag2, 0, b, s), 1u);
    } else if (tid < 128) {
        if (lane < 8) { while (aload32(TAG(tag2, 0, b, lane)) != 1u) {} }
        __builtin_amdgcn_fence(__ATOMIC_ACQUIRE, "agent");
    }
    __syncthreads();
    if (tid < 64) {
        float s0 = 0.f;
        const float* pb = PSLOT(0, 0);
        #pragma unroll
        for (int ss = 0; ss < 8; ++ss) {
            float2 p = ((const float2*)(pb + ss * 256))[lane];
            s0 += p.y;
        }
        float e = __expf(s0 * scale);
        float den = sum64(e);
        float r = __fdividef(e, den);
        r_l[lane] = r;       // c1 (a=0)
        a_l[lane] = 0.f;
    } else if (tid >= 128 && tid < 192) {
        xp_s[tid - 128] = out[((size_t)(b * TT)) * DD + d0 + (tid - 128)];
    } else if (tid >= 192 && tid < 256) {
        z_s[tid - 192] = Zbuf[((size_t)(b * TT)) * DD + d0 + (tid - 192)];
    }
    __syncthreads();
    {   // init rv partials
        const int nc = tid >> 6, d = tid & 63;
        float acc = 0.f;
        #pragma unroll
        for (int i = 0; i < 8; ++i) acc += r_l[nc * 8 + i] * tape[nc * 8 + i][d];
        red[nc][d] = acc;
    }
    __syncthreads();
    if (tid < 64) {
        float acc = 0.f;   // c2 = 0 at init
        #pragma unroll
        for (int nc = 0; nc < 8; ++nc) acc += red[nc][tid];
        rv[tid] = acc;
    }
    __syncthreads();

    // ---------------- main scan ----------------
    for (int t = 0; t < TT; ++t) {
        const int par = t & 1;
        const int par2 = (t + 1) & 1;
        const u32 tgt1 = (u32)(t + 1);
        const u32 tgt2 = (u32)(t + 2);
        float* hb = hbuf + ((size_t)par * 8 + b) * 512;

        // S1 produce (wave0): h_new = tanh(hh + xp + rv + bh); plain store + fence + tag
        if (tid < 64) {
            float hn = fast_tanh(hh_s[lane] + xp_s[lane] + rv[lane] + bh_s[lane]);
            hn_s[lane] = hn;
            hb[d0 + lane] = hn;
            __builtin_amdgcn_fence(__ATOMIC_RELEASE, "agent");
            if (lane == 0) astore32(TAG(tag1, par, b, s), tgt1);
        } else if (tid >= 128 && tid < 192) {
            // S1 poll (wave2)
            if (lane < 8) { while (aload32(TAG(tag1, par, b, lane)) != tgt1) {} }
            __builtin_amdgcn_fence(__ATOMIC_ACQUIRE, "agent");
        }
        __syncthreads();   // B1: inv done before plain h loads
        // gather h(t): all 512 threads, coalesced plain loads; wave1 also epilogue
        {
            float hval = hb[tid];
            hw2[tid >> 6][tid & 63] = hval;
            if (tid >= 64 && tid < 128) {
                const int d = lane;
                const float h = hn_s[d];
                float g = z_s[d] * gzr + rv[d] * grr + h * ghr + bgr;
                g = fminf(fmaxf(g, -20.f), 20.f);
                const float sig = 1.f / (1.f + __expf(-g));
                out[((size_t)(b * TT + t)) * DD + d0 + d] = h * g * sig;
            }
        }
        __syncthreads();   // B2
        // wv = W_write . h(t)
        {
            float acc = dot64(ww, &hw2[l][0]);
            acc = redux8(acc);
            if (l == 0) wv_s[row] = acc;
        }
        __syncthreads();   // B3
        // score partials vs OLD tape
        {
            float accw = 0.f, acc0 = 0.f;
            #pragma unroll
            for (int i = 0; i < 8; ++i) {
                const int dl = l * 8 + i;
                const float tp = tape[row][dl];
                accw += wv_s[dl] * tp;
                acc0 += hn_s[dl] * tp;
            }
            accw = redux8(accw);
            acc0 = redux8(acc0);
            if (l == 0) { pws_s[row] = accw; ps0_s[row] = acc0; }
        }
        __syncthreads();   // B4
        // S2 produce (wave0) then hh' = W_h.h(t) (all); wave1 polls S2 after its hh' part
        if (tid < 64) {
            float* ps = PSLOT(par2, s);
            float2 pp; pp.x = pws_s[lane]; pp.y = ps0_s[lane];
            ((float2*)ps)[lane] = pp;
            float hv = sum64(hn_s[lane] * wv_s[lane]);
            if (lane == 0) ps[128] = hv;
            __builtin_amdgcn_fence(__ATOMIC_RELEASE, "agent");
            if (lane == 0) astore32(TAG(tag2, par2, b, s), tgt2);
        }
        {
            float acc = dot64(wh, &hw2[l][0]);
            acc = redux8(acc);
            if (l == 0) hh_s[row] = acc;
        }
        if (tid >= 64 && tid < 128) {
            if (lane < 8) { while (aload32(TAG(tag2, par2, b, lane)) != tgt2) {} }
            __builtin_amdgcn_fence(__ATOMIC_ACQUIRE, "agent");
        }
        __syncthreads();   // B5
        // S2 consume (wave0): reduce partials + softmaxes; waves 2/3 prefetch t+1
        if (tid < 64) {
            const float* pb = PSLOT(par2, 0);
            float ws = 0.f, s0 = 0.f, hwv = 0.f;
            #pragma unroll
            for (int ss = 0; ss < 8; ++ss) {
                float2 p = ((const float2*)(pb + ss * 256))[lane];
                ws += p.x; s0 += p.y;
                hwv += pb[ss * 256 + 128];
            }
            float ew = __expf(ws * scale);
            float dw = sum64(ew);
            const float a = __fdividef(ew, dw);
            a_l[lane] = a;
            const float scn = scale * ((1.f - a) * s0 + a * hwv);
            float er = __expf(scn);
            float dr = sum64(er);
            const float r = __fdividef(er, dr);
            r_l[lane] = r * (1.f - a);          // c1
            float c2 = sum64(r * a);
            if (lane == 0) c2_s = c2;
        } else if (tid >= 128 && tid < 192) {
            const int tn = (t + 1 < TT) ? (t + 1) : t;
            xp_s[lane] = out[((size_t)(b * TT + tn)) * DD + d0 + lane];
        } else if (tid >= 192 && tid < 256) {
            const int tn = (t + 1 < TT) ? (t + 1) : t;
            z_s[lane] = Zbuf[((size_t)(b * TT + tn)) * DD + d0 + lane];
        }
        __syncthreads();   // B6
        // rv partials over OLD tape with c1
        {
            const int nc = tid >> 6, d = tid & 63;
            float acc = 0.f;
            #pragma unroll
            for (int i = 0; i < 8; ++i) acc += r_l[nc * 8 + i] * tape[nc * 8 + i][d];
            red[nc][d] = acc;
        }
        __syncthreads();   // B7
        // rv combine (wave0) + tape lerp (all)
        if (tid < 64) {
            float acc = c2_s * wv_s[tid];
            #pragma unroll
            for (int nc = 0; nc < 8; ++nc) acc += red[nc][tid];
            rv[tid] = acc;
        }
        {
            const float an = a_l[row];
            #pragma unroll
            for (int i = 0; i < 8; i += 4) {
                float4 tp = *(const float4*)&tape[row][l * 8 + i];
                float4 w4 = *(const float4*)&wv_s[l * 8 + i];
                tp.x += an * (w4.x - tp.x);
                tp.y += an * (w4.y - tp.y);
                tp.z += an * (w4.z - tp.z);
                tp.w += an * (w4.w - tp.w);
                *(float4*)&tape[row][l * 8 + i] = tp;
            }
        }
        __syncthreads();   // B8
    }

    // final tape slice -> output
    {
        float4 t0 = *(const float4*)&tape[row][l * 8];
        float4 t1 = *(const float4*)&tape[row][l * 8 + 4];
        float* dst = tape_out + ((size_t)(b * NT + row)) * DD + d0 + l * 8;
        *(float4*)dst = t0;
        *(float4*)(dst + 4) = t1;
    }
    #undef TAG
    #undef PSLOT
}

extern "C" void kernel_launch(void* const* d_in, const int* in_sizes, int n_in,
                              void* d_out, int out_size, void* d_ws, size_t ws_size,
                              hipStream_t stream) {
    const float* x       = (const float*)d_in[0];   // [8,1024,512]
    const float* tape0   = (const float*)d_in[1];   // [8,64,512]
    const float* hwork0  = (const float*)d_in[2];   // [8,512]
    const float* W_h     = (const float*)d_in[3];   // [512,512]
    const float* W_xz    = (const float*)d_in[4];   // [1024,512]
    const float* b_h     = (const float*)d_in[5];   // [512]
    const float* W_write = (const float*)d_in[6];   // [512,512]
    const float* g_z     = (const float*)d_in[7];
    const float* g_r     = (const float*)d_in[8];
    const float* g_h     = (const float*)d_in[9];
    const float* b_gate  = (const float*)d_in[10];

    float* out  = (float*)d_out;                       // outs [8,1024,512]
    float* tout = out + (size_t)BB * TT * DD;          // tape_final [8,64,512]

    char* ws = (char*)d_ws;
    u32* tag1   = (u32*)ws;                            // [2][8][8] x 64B = 8 KB
    u32* tag2   = (u32*)(ws + 8192);                   // 8 KB
    float* hbuf = (float*)(ws + 16384);                // [2][8][512] = 32 KB
    float* pbuf = (float*)(ws + 49152);                // [2][8][8]x256 floats = 128 KB
    float* Zbuf = (float*)(ws + 262144);               // 16 MB

    (void)in_sizes; (void)n_in; (void)out_size; (void)ws_size;

    // tags start poisoned 0xAAAAAAAA by harness; equality-polls never match poison.
    dim3 pgrid(128, 16);
    proj_kernel<<<pgrid, 256, 0, stream>>>(x, W_xz, out, Zbuf);
    rec_kernel<<<64, 512, 0, stream>>>(tape0, hwork0, W_h, b_h, W_write,
                                       g_z, g_r, g_h, b_gate, Zbuf,
                                       out, tout, tag1, tag2, hbuf, pbuf);
}